// Round 16
// baseline (298.844 us; speedup 1.0000x reference)
//
#include <hip/hip_runtime.h>
#include <hip/hip_bf16.h>

#define NN 100000
#define MM 32
#define NCAPS_ 8
#define HH 64
#define FAN 512  // NCAPS*H

typedef __attribute__((ext_vector_type(8))) short bf16x8;
typedef __attribute__((ext_vector_type(4))) short bf16x4;
typedef __attribute__((ext_vector_type(4))) float f32x4;

__device__ inline short f2bf(float f) {
  union { float f; unsigned u; } v; v.f = f;
  unsigned u = v.u;
  u += 0x7FFFu + ((u >> 16) & 1u);   // round-to-nearest-even
  return (short)(u >> 16);
}

__device__ inline bf16x8 cvt8(f32x4 lo, f32x4 hi) {
  bf16x8 r;
  r[0] = f2bf(lo[0]); r[1] = f2bf(lo[1]); r[2] = f2bf(lo[2]); r[3] = f2bf(lo[3]);
  r[4] = f2bf(hi[0]); r[5] = f2bf(hi[1]); r[6] = f2bf(hi[2]); r[7] = f2bf(hi[3]);
  return r;
}

// ---------------------------------------------------------------------------
// W f32 -> bf16 (512 KB, ~2 us)
// ---------------------------------------------------------------------------
__global__ __launch_bounds__(256) void conv_kernel(
    const float* __restrict__ src, short* __restrict__ dst) {
  const int i = (blockIdx.x * 256 + threadIdx.x) * 8;
  f32x4 lo = *(const f32x4*)(src + i);
  f32x4 hi = *(const f32x4*)(src + i + 4);
  *(bf16x8*)(dst + i) = cvt8(lo, hi);
}

// ---------------------------------------------------------------------------
// Kernel A v4: f32-DIRECT gather (deletes conv_x), 4 nodes/wave.
// lane = (ns = lane>>4: node, sub = lane&15: 16-B f32 chunk of the 256-B row).
// Edge offsets packed as  nb*2048 + rl*256 | valid  (rl recoverable from
// bits 8..10, valid from bit 0; invalid edges clamp to row 0 and zero).
// 4 batches of 8 gathers, 2-deep software pipeline (issue B while consuming A)
// -> no per-iteration vmcnt drain.  All array indices compile-time (rule #20).
// Accumulate acc[8 rel][4 f32] via predicated fma; residual + bf16 store.
// ---------------------------------------------------------------------------
__device__ __forceinline__ void aggf_consume(
    const int (&go)[8], const f32x4 (&v)[8], float (&acc)[NCAPS_][4]) {
#pragma unroll
  for (int j = 0; j < 8; ++j) {
    const int g  = go[j];
    const int rl = (g >> 8) & 7;
    const float mv = (float)(g & 1);
#pragma unroll
    for (int r = 0; r < NCAPS_; ++r) {
      const float mr = (rl == r) ? mv : 0.f;
#pragma unroll
      for (int q = 0; q < 4; ++q) acc[r][q] = fmaf(v[j][q], mr, acc[r][q]);
    }
  }
}

__global__ __launch_bounds__(256) void aggf_kernel(
    const float* __restrict__ x,
    const int* __restrict__ nb_node,
    const int* __restrict__ nb_rel,
    unsigned short* __restrict__ vbf) {
  const int tid   = threadIdx.x;
  const int wid   = tid >> 6;
  const int lane  = tid & 63;
  const int node0 = blockIdx.x * 16 + wid * 4;   // 6250 blocks * 16 == NN
  const int ns    = lane >> 4;                   // 0..3
  const int sub   = lane & 15;                   // 16-B chunk (4 floats)
  const int node  = node0 + ns;
  const int sub16 = sub * 16;

  // 128 (nb,rl) pairs for the wave's 4 nodes; lane holds pairs 2l, 2l+1.
  const int ibase = node0 * MM;
  const int2 nb2 = *(const int2*)(nb_node + ibase + lane * 2);
  const int2 rl2 = *(const int2*)(nb_rel  + ibase + lane * 2);
  const int pk0 = ((nb2.x < NN) ? (nb2.x * 2048 + rl2.x * 256 + 1) : (rl2.x * 256));
  const int pk1 = ((nb2.y < NN) ? (nb2.y * 2048 + rl2.y * 256 + 1) : (rl2.y * 256));

  const char* xb = (const char*)x;

  float acc[NCAPS_][4];
#pragma unroll
  for (int r = 0; r < NCAPS_; ++r)
#pragma unroll
    for (int q = 0; q < 4; ++q) acc[r][q] = 0.f;

  int goA[8], goB[8];
  f32x4 vA[8], vB[8];

  // edge i of my node ns lives at lane ns*16 + i/2, slot i&1
#define SHFL_Q(Q, GO)                                                     \
  _Pragma("unroll")                                                       \
  for (int j = 0; j < 8; ++j) {                                           \
    const int i = (Q) * 8 + j;                                            \
    GO[j] = __shfl((i & 1) ? pk1 : pk0, ns * 16 + (i >> 1));              \
  }
#define ISSUE(GO, V)                                                      \
  _Pragma("unroll")                                                       \
  for (int j = 0; j < 8; ++j)                                             \
    V[j] = *(const f32x4*)(xb + (size_t)(unsigned)(GO[j] & ~1) + sub16);

  SHFL_Q(0, goA) ISSUE(goA, vA)
  SHFL_Q(1, goB) ISSUE(goB, vB)
  aggf_consume(goA, vA, acc);
  SHFL_Q(2, goA) ISSUE(goA, vA)
  aggf_consume(goB, vB, acc);
  SHFL_Q(3, goB) ISSUE(goB, vB)
  aggf_consume(goA, vA, acc);

  // residual loads issued while last gather batch is in flight
  const char* xrow = xb + (size_t)node * 2048;
  f32x4 xr[NCAPS_];
#pragma unroll
  for (int r = 0; r < NCAPS_; ++r)
    xr[r] = *(const f32x4*)(xrow + r * 256 + sub16);

  aggf_consume(goB, vB, acc);

#undef SHFL_Q
#undef ISSUE

  // output: lane owns 4 bf16 (8 B) per relation of its node row
  unsigned short* vrow = vbf + (size_t)node * FAN;
#pragma unroll
  for (int r = 0; r < NCAPS_; ++r) {
    bf16x4 h;
#pragma unroll
    for (int q = 0; q < 4; ++q) h[q] = f2bf(acc[r][q] + xr[r][q]);
    *(bf16x4*)(vrow + r * HH + sub * 4) = h;
  }
}

// ---------------------------------------------------------------------------
// Kernel B (r15, frozen): out = relu(vbf @ Wbf^T + b).  BM=128 BN=256 BK=32,
// rb-fast, 2-bit slot swizzle (bank-conflict=0), triple buffer, single
// barrier per K-step, counted vmcnt(3).
// ---------------------------------------------------------------------------
#define BM 128
#define BN 256
#define BK 32
#define NRB ((NN + BM - 1) / BM)   // 782
#define NKB (FAN / BK)             // 16

__global__ __launch_bounds__(512, 2) void gemm_bf_kernel(
    const short* __restrict__ vbf,   // [NN][FAN] bf16
    const short* __restrict__ Wbf,   // [FAN][FAN] bf16 (row-major W)
    const float* __restrict__ bias,
    float* __restrict__ out) {
  __shared__ short Ab[3][BM * BK];   // 3 x 8 KB
  __shared__ short Bb[3][BN * BK];   // 3 x 16 KB

  const int rb = blockIdx.x % NRB;
  const int cb = blockIdx.x / NRB;   // 0..1

  const int tid  = threadIdx.x;
  const int lane = tid & 63;
  const int wave = tid >> 6;          // 0..7
  const int wr = wave >> 2;           // 0..1 row half
  const int wc = wave & 3;            // 0..3 col quarter
  const int l15 = lane & 15, kg = lane >> 4;

  const int row0 = rb * BM, col0 = cb * BN;

  f32x4 acc[4][4];
#pragma unroll
  for (int rf = 0; rf < 4; ++rf)
#pragma unroll
    for (int cf = 0; cf < 4; ++cf) acc[rf][cf] = (f32x4){0.f, 0.f, 0.f, 0.f};

  auto stage = [&](int buf, int kb) {
    {
      const int byteoff = tid * 16;
      const int arl  = byteoff >> 6;               // local row 0..127
      const int slot = (byteoff >> 4) & 3;
      const int ksw  = (slot ^ ((arl >> 1) & 3)) << 4;
      int arow = row0 + arl;
      if (arow >= NN) arow = NN - 1;               // clamp (store guarded)
      const char* asrc = (const char*)vbf + (size_t)arow * 1024 + kb * 64 + ksw;
      char* adst = (char*)(&Ab[buf][0]) + byteoff;
      __builtin_amdgcn_global_load_lds(
          (const __attribute__((address_space(1))) void*)asrc,
          (__attribute__((address_space(3))) void*)adst, 16, 0, 0);
    }
#pragma unroll
    for (int p = 0; p < 2; ++p) {
      const int byteoff = p * 8192 + tid * 16;
      const int cl   = byteoff >> 6;               // local col 0..255
      const int slot = (byteoff >> 4) & 3;
      const int ksw  = (slot ^ ((cl >> 1) & 3)) << 4;
      const char* bsrc = (const char*)Wbf + (size_t)(col0 + cl) * 1024 + kb * 64 + ksw;
      char* bdst = (char*)(&Bb[buf][0]) + byteoff;
      __builtin_amdgcn_global_load_lds(
          (const __attribute__((address_space(1))) void*)bsrc,
          (__attribute__((address_space(3))) void*)bdst, 16, 0, 0);
    }
  };

  stage(0, 0);
  stage(1, 1);   // 6 loads in flight

  for (int kb = 0; kb < NKB; ++kb) {
    const int cur = kb % 3;
    if (kb + 1 < NKB) {
      asm volatile("s_waitcnt vmcnt(3)" ::: "memory");  // tile kb landed
    } else {
      asm volatile("s_waitcnt vmcnt(0)" ::: "memory");
    }
    __builtin_amdgcn_s_barrier();                  // cur ready AND prev consumed
    __builtin_amdgcn_sched_barrier(0);

    if (kb + 2 < NKB) stage((kb + 2) % 3, kb + 2); // overwrite prev buf (safe)

    bf16x8 af[4], bfr[4];
#pragma unroll
    for (int rf = 0; rf < 4; ++rf) {
      const int row = wr * 64 + rf * 16 + l15;     // 0..127
      const int kby = (kg ^ ((row >> 1) & 3)) << 4;
      af[rf] = *(const bf16x8*)((const char*)&Ab[cur][0] + row * 64 + kby);
    }
#pragma unroll
    for (int cf = 0; cf < 4; ++cf) {
      const int col = wc * 64 + cf * 16 + l15;     // 0..255
      const int kby = (kg ^ ((col >> 1) & 3)) << 4;
      bfr[cf] = *(const bf16x8*)((const char*)&Bb[cur][0] + col * 64 + kby);
    }

#pragma unroll
    for (int rf = 0; rf < 4; ++rf)
#pragma unroll
      for (int cf = 0; cf < 4; ++cf)
        acc[rf][cf] = __builtin_amdgcn_mfma_f32_16x16x32_bf16(
            af[rf], bfr[cf], acc[rf][cf], 0, 0, 0);
  }

  // epilogue: bias + relu + store.  D: col=l15, row=kg*4+r within frag.
#pragma unroll
  for (int cf = 0; cf < 4; ++cf) {
    const int col = col0 + wc * 64 + cf * 16 + l15;
    const float bb = bias[col];
#pragma unroll
    for (int rf = 0; rf < 4; ++rf) {
#pragma unroll
      for (int r = 0; r < 4; ++r) {
        const int row = row0 + wr * 64 + rf * 16 + kg * 4 + r;
        if (row < NN) {
          float val = acc[rf][cf][r] + bb;
          out[(size_t)row * FAN + col] = val > 0.f ? val : 0.f;
        }
      }
    }
  }
}

// ---------------------------------------------------------------------------
// Fallback path (ws too small): round-6 proven f32 agg + f32 GEMM via d_out.
// ---------------------------------------------------------------------------
__global__ __launch_bounds__(256) void agg_fb_kernel(
    const float* __restrict__ x,
    const int* __restrict__ nb_node,
    const int* __restrict__ nb_rel,
    float* __restrict__ vf32) {
  const int wid  = __builtin_amdgcn_readfirstlane((int)(threadIdx.x >> 6));
  const int node = blockIdx.x * 4 + wid;
  const int lane = threadIdx.x & 63;

  const int eidx = node * MM + (lane & 31);
  const int pk = nb_node[eidx] | (nb_rel[eidx] << 20);

  int nbs[MM], rls[MM];
#pragma unroll
  for (int e = 0; e < MM; ++e) {
    const int p = __builtin_amdgcn_readlane(pk, e);
    nbs[e] = p & 0xFFFFF;
    rls[e] = (p >> 20) & 7;
  }

  float vf[MM];
#pragma unroll
  for (int e = 0; e < MM; ++e) {
    const int nbc = (nbs[e] < NN) ? nbs[e] : node;
    vf[e] = x[nbc * FAN + rls[e] * HH + lane];
  }
  float xr[NCAPS_];
  const int ob = node * FAN;
#pragma unroll
  for (int r = 0; r < NCAPS_; ++r) xr[r] = x[ob + r * HH + lane];

  float acc[NCAPS_];
#pragma unroll
  for (int r = 0; r < NCAPS_; ++r) acc[r] = 0.f;
#pragma unroll
  for (int e = 0; e < MM; ++e) {
    if (nbs[e] < NN) {
      const float val = vf[e];
      switch (rls[e]) {
        case 0: acc[0] += val; break;
        case 1: acc[1] += val; break;
        case 2: acc[2] += val; break;
        case 3: acc[3] += val; break;
        case 4: acc[4] += val; break;
        case 5: acc[5] += val; break;
        case 6: acc[6] += val; break;
        case 7: acc[7] += val; break;
      }
    }
  }
#pragma unroll
  for (int r = 0; r < NCAPS_; ++r)
    vf32[ob + r * HH + lane] = acc[r] + xr[r];
}

__global__ __launch_bounds__(256) void gemm_f32_kernel(
    const float* vin, const float* __restrict__ W,
    const float* __restrict__ bias, float* out) {
  const int lane = threadIdx.x & 63;
  const int wave = threadIdx.x >> 6;
  const int row0 = blockIdx.x * 64;
  const int col0 = wave * 128;
  const int l15  = lane & 15;
  const int kg   = lane >> 4;

  f32x4 acc[4][8];
#pragma unroll
  for (int rf = 0; rf < 4; ++rf)
#pragma unroll
    for (int c = 0; c < 8; ++c) acc[rf][c] = (f32x4){0.f, 0.f, 0.f, 0.f};

  for (int kb = 0; kb < FAN / 32; ++kb) {
    const int k0 = kb * 32 + kg * 8;
    bf16x8 afrag[4];
#pragma unroll
    for (int rf = 0; rf < 4; ++rf) {
      int row = row0 + rf * 16 + l15;
      if (row >= NN) row = NN - 1;
      const float* p = vin + (size_t)row * FAN + k0;
      afrag[rf] = cvt8(*(const f32x4*)p, *(const f32x4*)(p + 4));
    }
#pragma unroll
    for (int c = 0; c < 8; ++c) {
      const int col = col0 + c * 16 + l15;
      const float* q = W + (size_t)col * FAN + k0;
      bf16x8 bfrag = cvt8(*(const f32x4*)q, *(const f32x4*)(q + 4));
#pragma unroll
      for (int rf = 0; rf < 4; ++rf)
        acc[rf][c] = __builtin_amdgcn_mfma_f32_16x16x32_bf16(
            afrag[rf], bfrag, acc[rf][c], 0, 0, 0);
    }
  }

#pragma unroll
  for (int c = 0; c < 8; ++c) {
    const int col = col0 + c * 16 + l15;
    const float bb = bias[col];
#pragma unroll
    for (int rf = 0; rf < 4; ++rf)
#pragma unroll
      for (int r = 0; r < 4; ++r) {
        const int row = row0 + rf * 16 + kg * 4 + r;
        if (row < NN) {
          float val = acc[rf][c][r] + bb;
          out[(size_t)row * FAN + col] = val > 0.f ? val : 0.f;
        }
      }
  }
}

extern "C" void kernel_launch(void* const* d_in, const int* in_sizes, int n_in,
                              void* d_out, int out_size, void* d_ws, size_t ws_size,
                              hipStream_t stream) {
  const float* x  = (const float*)d_in[0];
  const float* W  = (const float*)d_in[1];
  const float* b  = (const float*)d_in[2];
  const int*   nn = (const int*)d_in[3];
  const int*   nr = (const int*)d_in[4];
  float* out = (float*)d_out;

  const size_t wbf_bytes = (size_t)FAN * FAN * sizeof(short);        // 512 KB
  const size_t vbf_bytes = (size_t)NN * FAN * sizeof(short);         // 102.4 MB

  short* Wbf = (short*)d_ws;
  short* vbf = (short*)((char*)d_ws + wbf_bytes);

  if (ws_size >= wbf_bytes + vbf_bytes) {
    conv_kernel<<<FAN * FAN / (256 * 8), 256, 0, stream>>>(W, Wbf);
    aggf_kernel<<<NN / 16, 256, 0, stream>>>(x, nn, nr, (unsigned short*)vbf);
    gemm_bf_kernel<<<NRB * (FAN / BN), 512, 0, stream>>>(vbf, Wbf, b, out);
  } else {
    agg_fb_kernel<<<NN / 4, 256, 0, stream>>>(x, nn, nr, out);
    gemm_f32_kernel<<<(NN + 63) / 64, 256, 0, stream>>>(out, W, b, out);
  }
}

// Round 17
// 277.171 us; speedup vs baseline: 1.0782x; 1.0782x over previous
//
#include <hip/hip_runtime.h>
#include <hip/hip_bf16.h>

#define NN 100000
#define MM 32
#define NCAPS_ 8
#define HH 64
#define FAN 512  // NCAPS*H

typedef __attribute__((ext_vector_type(8))) short bf16x8;
typedef __attribute__((ext_vector_type(4))) float f32x4;
typedef __attribute__((ext_vector_type(4))) int   i32x4;

__device__ inline short f2bf(float f) {
  union { float f; unsigned u; } v; v.f = f;
  unsigned u = v.u;
  u += 0x7FFFu + ((u >> 16) & 1u);   // round-to-nearest-even
  return (short)(u >> 16);
}

__device__ inline float bf2f(unsigned short us) {
  union { unsigned u; float f; } c;
  c.u = ((unsigned)us) << 16;
  return c.f;
}

__device__ inline bf16x8 cvt8(f32x4 lo, f32x4 hi) {
  bf16x8 r;
  r[0] = f2bf(lo[0]); r[1] = f2bf(lo[1]); r[2] = f2bf(lo[2]); r[3] = f2bf(lo[3]);
  r[4] = f2bf(hi[0]); r[5] = f2bf(hi[1]); r[6] = f2bf(hi[2]); r[7] = f2bf(hi[3]);
  return r;
}

// ---------------------------------------------------------------------------
// f32 -> bf16 streaming conversion (runs at HBM BW peak)
// ---------------------------------------------------------------------------
__global__ __launch_bounds__(256) void conv_kernel(
    const float* __restrict__ src, short* __restrict__ dst) {
  const int i = (blockIdx.x * 256 + threadIdx.x) * 8;
  f32x4 lo = *(const f32x4*)(src + i);
  f32x4 hi = *(const f32x4*)(src + i + 4);
  *(bf16x8*)(dst + i) = cvt8(lo, hi);
}

// ---------------------------------------------------------------------------
// Kernel A v5: bf16 gathers (r8 numerics) + r16's explicit 2-deep batched
// software pipeline.  One wave = 8 nodes; lane = (ns = lane>>3: node,
// sub = lane&7: 16-B chunk of the 128-B bf16 row).  4 batches x 8 gathers;
// batch k+1 issued before batch k is consumed -> consume waits at vmcnt(8),
// never a full drain.  Offsets packed nb*1024 + rl*128 | valid (rl bits 7..9,
// valid bit 0; +sub*16 <= 112 never carries into bit 7).
// ---------------------------------------------------------------------------
__device__ __forceinline__ void agg_consume(
    const int (&go)[8], const bf16x8 (&v)[8], float (&acc)[NCAPS_][8]) {
#pragma unroll
  for (int j = 0; j < 8; ++j) {
    const int rl = (go[j] >> 7) & 7;
    const float mv = (float)(go[j] & 1);
    float f[8];
#pragma unroll
    for (int q = 0; q < 8; ++q) f[q] = bf2f((unsigned short)v[j][q]);
#pragma unroll
    for (int r = 0; r < NCAPS_; ++r) {
      const float mr = (rl == r) ? mv : 0.f;
#pragma unroll
      for (int q = 0; q < 8; ++q) acc[r][q] = fmaf(f[q], mr, acc[r][q]);
    }
  }
}

__global__ __launch_bounds__(256) void agg3_kernel(
    const unsigned short* __restrict__ xbf,
    const int* __restrict__ nb_node,
    const int* __restrict__ nb_rel,
    unsigned short* __restrict__ vbf) {
  const int tid   = threadIdx.x;
  const int wid   = tid >> 6;
  const int lane  = tid & 63;
  const int node0 = blockIdx.x * 32 + wid * 8;   // 3125 blocks * 32 == NN
  const int ns    = lane >> 3;
  const int sub   = lane & 7;
  const int node  = node0 + ns;
  const int sub16 = sub * 16;

  // 256 (nb,rl) pairs; lane holds pairs 4l..4l+3.  Pack byte offsets.
  const i32x4 nb4 = ((const i32x4*)(nb_node + node0 * MM))[lane];
  const i32x4 rl4 = ((const i32x4*)(nb_rel  + node0 * MM))[lane];
  int pk[4];
#pragma unroll
  for (int j = 0; j < 4; ++j)
    pk[j] = (nb4[j] < NN) ? (nb4[j] * 1024 + rl4[j] * 128 + 1) : (rl4[j] * 128);

  const char* xb = (const char*)xbf;

  float acc[NCAPS_][8];
#pragma unroll
  for (int r = 0; r < NCAPS_; ++r)
#pragma unroll
    for (int q = 0; q < 8; ++q) acc[r][q] = 0.f;

  int goA[8], goB[8];
  bf16x8 vA[8], vB[8];

  // edge i of node ns lives at lane ns*8 + i/4, component i&3  (i = Q*8+j)
#define SHFL_Q(Q, GO)                                                     \
  _Pragma("unroll")                                                       \
  for (int j = 0; j < 8; ++j)                                             \
    GO[j] = __shfl(pk[j & 3], ns * 8 + (Q) * 2 + (j >> 2));
#define ISSUE(GO, V)                                                      \
  _Pragma("unroll")                                                       \
  for (int j = 0; j < 8; ++j)                                             \
    V[j] = *(const bf16x8*)(xb + (size_t)(unsigned)(GO[j] & ~1) + sub16);

  SHFL_Q(0, goA) ISSUE(goA, vA)
  SHFL_Q(1, goB) ISSUE(goB, vB)
  agg_consume(goA, vA, acc);
  SHFL_Q(2, goA) ISSUE(goA, vA)
  agg_consume(goB, vB, acc);
  SHFL_Q(3, goB) ISSUE(goB, vB)
  agg_consume(goA, vA, acc);

  // residual loads issued while the last gather batch is in flight
  const char* xrow = xb + (size_t)node * 1024;
  bf16x8 xr[NCAPS_];
#pragma unroll
  for (int r = 0; r < NCAPS_; ++r)
    xr[r] = *(const bf16x8*)(xrow + r * 128 + sub16);

  agg_consume(goB, vB, acc);

#undef SHFL_Q
#undef ISSUE

  // output: lane owns 8 bf16 (16 B) per relation of its node row
  unsigned short* vrow = vbf + (size_t)node * FAN;
#pragma unroll
  for (int r = 0; r < NCAPS_; ++r) {
    f32x4 lo, hi;
#pragma unroll
    for (int q = 0; q < 4; ++q) {
      lo[q] = acc[r][q]     + bf2f((unsigned short)xr[r][q]);
      hi[q] = acc[r][q + 4] + bf2f((unsigned short)xr[r][q + 4]);
    }
    *(bf16x8*)(vrow + r * HH + sub * 8) = cvt8(lo, hi);
  }
}

// ---------------------------------------------------------------------------
// Kernel B (r15, frozen): out = relu(vbf @ Wbf^T + b).  BM=128 BN=256 BK=32,
// rb-fast, 2-bit slot swizzle (bank-conflict=0), triple buffer, single
// barrier per K-step, counted vmcnt(3).
// ---------------------------------------------------------------------------
#define BM 128
#define BN 256
#define BK 32
#define NRB ((NN + BM - 1) / BM)   // 782
#define NKB (FAN / BK)             // 16

__global__ __launch_bounds__(512, 2) void gemm_bf_kernel(
    const short* __restrict__ vbf,   // [NN][FAN] bf16
    const short* __restrict__ Wbf,   // [FAN][FAN] bf16 (row-major W)
    const float* __restrict__ bias,
    float* __restrict__ out) {
  __shared__ short Ab[3][BM * BK];   // 3 x 8 KB
  __shared__ short Bb[3][BN * BK];   // 3 x 16 KB

  const int rb = blockIdx.x % NRB;
  const int cb = blockIdx.x / NRB;   // 0..1

  const int tid  = threadIdx.x;
  const int lane = tid & 63;
  const int wave = tid >> 6;          // 0..7
  const int wr = wave >> 2;           // 0..1 row half
  const int wc = wave & 3;            // 0..3 col quarter
  const int l15 = lane & 15, kg = lane >> 4;

  const int row0 = rb * BM, col0 = cb * BN;

  f32x4 acc[4][4];
#pragma unroll
  for (int rf = 0; rf < 4; ++rf)
#pragma unroll
    for (int cf = 0; cf < 4; ++cf) acc[rf][cf] = (f32x4){0.f, 0.f, 0.f, 0.f};

  auto stage = [&](int buf, int kb) {
    {
      const int byteoff = tid * 16;
      const int arl  = byteoff >> 6;               // local row 0..127
      const int slot = (byteoff >> 4) & 3;
      const int ksw  = (slot ^ ((arl >> 1) & 3)) << 4;
      int arow = row0 + arl;
      if (arow >= NN) arow = NN - 1;               // clamp (store guarded)
      const char* asrc = (const char*)vbf + (size_t)arow * 1024 + kb * 64 + ksw;
      char* adst = (char*)(&Ab[buf][0]) + byteoff;
      __builtin_amdgcn_global_load_lds(
          (const __attribute__((address_space(1))) void*)asrc,
          (__attribute__((address_space(3))) void*)adst, 16, 0, 0);
    }
#pragma unroll
    for (int p = 0; p < 2; ++p) {
      const int byteoff = p * 8192 + tid * 16;
      const int cl   = byteoff >> 6;               // local col 0..255
      const int slot = (byteoff >> 4) & 3;
      const int ksw  = (slot ^ ((cl >> 1) & 3)) << 4;
      const char* bsrc = (const char*)Wbf + (size_t)(col0 + cl) * 1024 + kb * 64 + ksw;
      char* bdst = (char*)(&Bb[buf][0]) + byteoff;
      __builtin_amdgcn_global_load_lds(
          (const __attribute__((address_space(1))) void*)bsrc,
          (__attribute__((address_space(3))) void*)bdst, 16, 0, 0);
    }
  };

  stage(0, 0);
  stage(1, 1);   // 6 loads in flight

  for (int kb = 0; kb < NKB; ++kb) {
    const int cur = kb % 3;
    if (kb + 1 < NKB) {
      asm volatile("s_waitcnt vmcnt(3)" ::: "memory");  // tile kb landed
    } else {
      asm volatile("s_waitcnt vmcnt(0)" ::: "memory");
    }
    __builtin_amdgcn_s_barrier();                  // cur ready AND prev consumed
    __builtin_amdgcn_sched_barrier(0);

    if (kb + 2 < NKB) stage((kb + 2) % 3, kb + 2); // overwrite prev buf (safe)

    bf16x8 af[4], bfr[4];
#pragma unroll
    for (int rf = 0; rf < 4; ++rf) {
      const int row = wr * 64 + rf * 16 + l15;     // 0..127
      const int kby = (kg ^ ((row >> 1) & 3)) << 4;
      af[rf] = *(const bf16x8*)((const char*)&Ab[cur][0] + row * 64 + kby);
    }
#pragma unroll
    for (int cf = 0; cf < 4; ++cf) {
      const int col = wc * 64 + cf * 16 + l15;     // 0..255
      const int kby = (kg ^ ((col >> 1) & 3)) << 4;
      bfr[cf] = *(const bf16x8*)((const char*)&Bb[cur][0] + col * 64 + kby);
    }

#pragma unroll
    for (int rf = 0; rf < 4; ++rf)
#pragma unroll
      for (int cf = 0; cf < 4; ++cf)
        acc[rf][cf] = __builtin_amdgcn_mfma_f32_16x16x32_bf16(
            af[rf], bfr[cf], acc[rf][cf], 0, 0, 0);
  }

  // epilogue: bias + relu + store.  D: col=l15, row=kg*4+r within frag.
#pragma unroll
  for (int cf = 0; cf < 4; ++cf) {
    const int col = col0 + wc * 64 + cf * 16 + l15;
    const float bb = bias[col];
#pragma unroll
    for (int rf = 0; rf < 4; ++rf) {
#pragma unroll
      for (int r = 0; r < 4; ++r) {
        const int row = row0 + wr * 64 + rf * 16 + kg * 4 + r;
        if (row < NN) {
          float val = acc[rf][cf][r] + bb;
          out[(size_t)row * FAN + col] = val > 0.f ? val : 0.f;
        }
      }
    }
  }
}

// ---------------------------------------------------------------------------
// Fallback path (ws too small): round-6 proven f32 agg + f32 GEMM via d_out.
// ---------------------------------------------------------------------------
__global__ __launch_bounds__(256) void agg_fb_kernel(
    const float* __restrict__ x,
    const int* __restrict__ nb_node,
    const int* __restrict__ nb_rel,
    float* __restrict__ vf32) {
  const int wid  = __builtin_amdgcn_readfirstlane((int)(threadIdx.x >> 6));
  const int node = blockIdx.x * 4 + wid;
  const int lane = threadIdx.x & 63;

  const int eidx = node * MM + (lane & 31);
  const int pk = nb_node[eidx] | (nb_rel[eidx] << 20);

  int nbs[MM], rls[MM];
#pragma unroll
  for (int e = 0; e < MM; ++e) {
    const int p = __builtin_amdgcn_readlane(pk, e);
    nbs[e] = p & 0xFFFFF;
    rls[e] = (p >> 20) & 7;
  }

  float vf[MM];
#pragma unroll
  for (int e = 0; e < MM; ++e) {
    const int nbc = (nbs[e] < NN) ? nbs[e] : node;
    vf[e] = x[nbc * FAN + rls[e] * HH + lane];
  }
  float xr[NCAPS_];
  const int ob = node * FAN;
#pragma unroll
  for (int r = 0; r < NCAPS_; ++r) xr[r] = x[ob + r * HH + lane];

  float acc[NCAPS_];
#pragma unroll
  for (int r = 0; r < NCAPS_; ++r) acc[r] = 0.f;
#pragma unroll
  for (int e = 0; e < MM; ++e) {
    if (nbs[e] < NN) {
      const float val = vf[e];
      switch (rls[e]) {
        case 0: acc[0] += val; break;
        case 1: acc[1] += val; break;
        case 2: acc[2] += val; break;
        case 3: acc[3] += val; break;
        case 4: acc[4] += val; break;
        case 5: acc[5] += val; break;
        case 6: acc[6] += val; break;
        case 7: acc[7] += val; break;
      }
    }
  }
#pragma unroll
  for (int r = 0; r < NCAPS_; ++r)
    vf32[ob + r * HH + lane] = acc[r] + xr[r];
}

__global__ __launch_bounds__(256) void gemm_f32_kernel(
    const float* vin, const float* __restrict__ W,
    const float* __restrict__ bias, float* out) {
  const int lane = threadIdx.x & 63;
  const int wave = threadIdx.x >> 6;
  const int row0 = blockIdx.x * 64;
  const int col0 = wave * 128;
  const int l15  = lane & 15;
  const int kg   = lane >> 4;

  f32x4 acc[4][8];
#pragma unroll
  for (int rf = 0; rf < 4; ++rf)
#pragma unroll
    for (int c = 0; c < 8; ++c) acc[rf][c] = (f32x4){0.f, 0.f, 0.f, 0.f};

  for (int kb = 0; kb < FAN / 32; ++kb) {
    const int k0 = kb * 32 + kg * 8;
    bf16x8 afrag[4];
#pragma unroll
    for (int rf = 0; rf < 4; ++rf) {
      int row = row0 + rf * 16 + l15;
      if (row >= NN) row = NN - 1;
      const float* p = vin + (size_t)row * FAN + k0;
      afrag[rf] = cvt8(*(const f32x4*)p, *(const f32x4*)(p + 4));
    }
#pragma unroll
    for (int c = 0; c < 8; ++c) {
      const int col = col0 + c * 16 + l15;
      const float* q = W + (size_t)col * FAN + k0;
      bf16x8 bfrag = cvt8(*(const f32x4*)q, *(const f32x4*)(q + 4));
#pragma unroll
      for (int rf = 0; rf < 4; ++rf)
        acc[rf][c] = __builtin_amdgcn_mfma_f32_16x16x32_bf16(
            afrag[rf], bfrag, acc[rf][c], 0, 0, 0);
    }
  }

#pragma unroll
  for (int c = 0; c < 8; ++c) {
    const int col = col0 + c * 16 + l15;
    const float bb = bias[col];
#pragma unroll
    for (int rf = 0; rf < 4; ++rf)
#pragma unroll
      for (int r = 0; r < 4; ++r) {
        const int row = row0 + rf * 16 + kg * 4 + r;
        if (row < NN) {
          float val = acc[rf][c][r] + bb;
          out[(size_t)row * FAN + col] = val > 0.f ? val : 0.f;
        }
      }
  }
}

extern "C" void kernel_launch(void* const* d_in, const int* in_sizes, int n_in,
                              void* d_out, int out_size, void* d_ws, size_t ws_size,
                              hipStream_t stream) {
  const float* x  = (const float*)d_in[0];
  const float* W  = (const float*)d_in[1];
  const float* b  = (const float*)d_in[2];
  const int*   nn = (const int*)d_in[3];
  const int*   nr = (const int*)d_in[4];
  float* out = (float*)d_out;

  const size_t wbf_bytes = (size_t)FAN * FAN * sizeof(short);        // 512 KB
  const size_t vbf_bytes = (size_t)NN * FAN * sizeof(short);         // 102.4 MB
  const size_t xbf_bytes = (size_t)NN * FAN * sizeof(short);         // 102.4 MB

  short* Wbf = (short*)d_ws;
  short* vbf = (short*)((char*)d_ws + wbf_bytes);
  short* xbf = (short*)((char*)d_ws + wbf_bytes + vbf_bytes);

  if (ws_size >= wbf_bytes + vbf_bytes + xbf_bytes) {
    conv_kernel<<<FAN * FAN / (256 * 8), 256, 0, stream>>>(W, Wbf);
    conv_kernel<<<NN * FAN / (256 * 8), 256, 0, stream>>>(x, xbf);
    agg3_kernel<<<NN / 32, 256, 0, stream>>>(
        (const unsigned short*)xbf, nn, nr, (unsigned short*)vbf);
    gemm_bf_kernel<<<NRB * (FAN / BN), 512, 0, stream>>>(vbf, Wbf, b, out);
  } else {
    agg_fb_kernel<<<NN / 4, 256, 0, stream>>>(x, nn, nr, out);
    gemm_f32_kernel<<<(NN + 63) / 64, 256, 0, stream>>>(out, W, b, out);
  }
}

// Round 18
// 256.737 us; speedup vs baseline: 1.1640x; 1.0796x over previous
//
#include <hip/hip_runtime.h>
#include <hip/hip_bf16.h>

#define NN 100000
#define MM 32
#define NCAPS_ 8
#define HH 64
#define FAN 512  // NCAPS*H

typedef __attribute__((ext_vector_type(8))) short bf16x8;
typedef __attribute__((ext_vector_type(4))) float f32x4;
typedef __attribute__((ext_vector_type(4))) int   i32x4;

__device__ inline short f2bf(float f) {
  union { float f; unsigned u; } v; v.f = f;
  unsigned u = v.u;
  u += 0x7FFFu + ((u >> 16) & 1u);   // round-to-nearest-even
  return (short)(u >> 16);
}

__device__ inline float bf2f(unsigned short us) {
  union { unsigned u; float f; } c;
  c.u = ((unsigned)us) << 16;
  return c.f;
}

__device__ inline bf16x8 cvt8(f32x4 lo, f32x4 hi) {
  bf16x8 r;
  r[0] = f2bf(lo[0]); r[1] = f2bf(lo[1]); r[2] = f2bf(lo[2]); r[3] = f2bf(lo[3]);
  r[4] = f2bf(hi[0]); r[5] = f2bf(hi[1]); r[6] = f2bf(hi[2]); r[7] = f2bf(hi[3]);
  return r;
}

// ---------------------------------------------------------------------------
// f32 -> bf16 streaming conversion.  NT=true: non-temporal source reads
// (x is read exactly once in the pipeline -- keep it OUT of L3 so the
// just-written xbf stays resident for agg's gathers).
// ---------------------------------------------------------------------------
template <bool NT>
__global__ __launch_bounds__(256) void conv_kernel(
    const float* __restrict__ src, short* __restrict__ dst) {
  const int i = (blockIdx.x * 256 + threadIdx.x) * 8;
  f32x4 lo, hi;
  if (NT) {
    lo = __builtin_nontemporal_load((const f32x4*)(src + i));
    hi = __builtin_nontemporal_load((const f32x4*)(src + i + 4));
  } else {
    lo = *(const f32x4*)(src + i);
    hi = *(const f32x4*)(src + i + 4);
  }
  *(bf16x8*)(dst + i) = cvt8(lo, hi);
}

// ---------------------------------------------------------------------------
// Kernel A v5 (r17): bf16 gathers + 2-deep batched software pipeline.
// One wave = 8 nodes; lane = (ns = lane>>3: node, sub = lane&7: 16-B chunk).
// 4 batches x 8 gathers, batch k+1 in flight while batch k is consumed.
// ---------------------------------------------------------------------------
__device__ __forceinline__ void agg_consume(
    const int (&go)[8], const bf16x8 (&v)[8], float (&acc)[NCAPS_][8]) {
#pragma unroll
  for (int j = 0; j < 8; ++j) {
    const int rl = (go[j] >> 7) & 7;
    const float mv = (float)(go[j] & 1);
    float f[8];
#pragma unroll
    for (int q = 0; q < 8; ++q) f[q] = bf2f((unsigned short)v[j][q]);
#pragma unroll
    for (int r = 0; r < NCAPS_; ++r) {
      const float mr = (rl == r) ? mv : 0.f;
#pragma unroll
      for (int q = 0; q < 8; ++q) acc[r][q] = fmaf(f[q], mr, acc[r][q]);
    }
  }
}

__global__ __launch_bounds__(256) void agg3_kernel(
    const unsigned short* __restrict__ xbf,
    const int* __restrict__ nb_node,
    const int* __restrict__ nb_rel,
    unsigned short* __restrict__ vbf) {
  const int tid   = threadIdx.x;
  const int wid   = tid >> 6;
  const int lane  = tid & 63;
  const int node0 = blockIdx.x * 32 + wid * 8;   // 3125 blocks * 32 == NN
  const int ns    = lane >> 3;
  const int sub   = lane & 7;
  const int node  = node0 + ns;
  const int sub16 = sub * 16;

  const i32x4 nb4 = ((const i32x4*)(nb_node + node0 * MM))[lane];
  const i32x4 rl4 = ((const i32x4*)(nb_rel  + node0 * MM))[lane];
  int pk[4];
#pragma unroll
  for (int j = 0; j < 4; ++j)
    pk[j] = (nb4[j] < NN) ? (nb4[j] * 1024 + rl4[j] * 128 + 1) : (rl4[j] * 128);

  const char* xb = (const char*)xbf;

  float acc[NCAPS_][8];
#pragma unroll
  for (int r = 0; r < NCAPS_; ++r)
#pragma unroll
    for (int q = 0; q < 8; ++q) acc[r][q] = 0.f;

  int goA[8], goB[8];
  bf16x8 vA[8], vB[8];

#define SHFL_Q(Q, GO)                                                     \
  _Pragma("unroll")                                                       \
  for (int j = 0; j < 8; ++j)                                             \
    GO[j] = __shfl(pk[j & 3], ns * 8 + (Q) * 2 + (j >> 2));
#define ISSUE(GO, V)                                                      \
  _Pragma("unroll")                                                       \
  for (int j = 0; j < 8; ++j)                                             \
    V[j] = *(const bf16x8*)(xb + (size_t)(unsigned)(GO[j] & ~1) + sub16);

  SHFL_Q(0, goA) ISSUE(goA, vA)
  SHFL_Q(1, goB) ISSUE(goB, vB)
  agg_consume(goA, vA, acc);
  SHFL_Q(2, goA) ISSUE(goA, vA)
  agg_consume(goB, vB, acc);
  SHFL_Q(3, goB) ISSUE(goB, vB)
  agg_consume(goA, vA, acc);

  const char* xrow = xb + (size_t)node * 1024;
  bf16x8 xr[NCAPS_];
#pragma unroll
  for (int r = 0; r < NCAPS_; ++r)
    xr[r] = *(const bf16x8*)(xrow + r * 128 + sub16);

  agg_consume(goB, vB, acc);

#undef SHFL_Q
#undef ISSUE

  unsigned short* vrow = vbf + (size_t)node * FAN;
#pragma unroll
  for (int r = 0; r < NCAPS_; ++r) {
    f32x4 lo, hi;
#pragma unroll
    for (int q = 0; q < 4; ++q) {
      lo[q] = acc[r][q]     + bf2f((unsigned short)xr[r][q]);
      hi[q] = acc[r][q + 4] + bf2f((unsigned short)xr[r][q + 4]);
    }
    *(bf16x8*)(vrow + r * HH + sub * 8) = cvt8(lo, hi);
  }
}

// ---------------------------------------------------------------------------
// Kernel B (r15 structure): out = relu(vbf @ Wbf^T + b).  BM=128 BN=256 BK=32,
// rb-fast, 2-bit slot swizzle (bank-conflict=0), triple buffer, single
// barrier per K-step, counted vmcnt(3).  NEW: non-temporal out stores
// (write-once data; keep it from evicting vbf between the 2 col passes).
// ---------------------------------------------------------------------------
#define BM 128
#define BN 256
#define BK 32
#define NRB ((NN + BM - 1) / BM)   // 782
#define NKB (FAN / BK)             // 16

__global__ __launch_bounds__(512, 2) void gemm_bf_kernel(
    const short* __restrict__ vbf,   // [NN][FAN] bf16
    const short* __restrict__ Wbf,   // [FAN][FAN] bf16 (row-major W)
    const float* __restrict__ bias,
    float* __restrict__ out) {
  __shared__ short Ab[3][BM * BK];   // 3 x 8 KB
  __shared__ short Bb[3][BN * BK];   // 3 x 16 KB

  const int rb = blockIdx.x % NRB;
  const int cb = blockIdx.x / NRB;   // 0..1

  const int tid  = threadIdx.x;
  const int lane = tid & 63;
  const int wave = tid >> 6;          // 0..7
  const int wr = wave >> 2;           // 0..1 row half
  const int wc = wave & 3;            // 0..3 col quarter
  const int l15 = lane & 15, kg = lane >> 4;

  const int row0 = rb * BM, col0 = cb * BN;

  f32x4 acc[4][4];
#pragma unroll
  for (int rf = 0; rf < 4; ++rf)
#pragma unroll
    for (int cf = 0; cf < 4; ++cf) acc[rf][cf] = (f32x4){0.f, 0.f, 0.f, 0.f};

  auto stage = [&](int buf, int kb) {
    {
      const int byteoff = tid * 16;
      const int arl  = byteoff >> 6;               // local row 0..127
      const int slot = (byteoff >> 4) & 3;
      const int ksw  = (slot ^ ((arl >> 1) & 3)) << 4;
      int arow = row0 + arl;
      if (arow >= NN) arow = NN - 1;               // clamp (store guarded)
      const char* asrc = (const char*)vbf + (size_t)arow * 1024 + kb * 64 + ksw;
      char* adst = (char*)(&Ab[buf][0]) + byteoff;
      __builtin_amdgcn_global_load_lds(
          (const __attribute__((address_space(1))) void*)asrc,
          (__attribute__((address_space(3))) void*)adst, 16, 0, 0);
    }
#pragma unroll
    for (int p = 0; p < 2; ++p) {
      const int byteoff = p * 8192 + tid * 16;
      const int cl   = byteoff >> 6;               // local col 0..255
      const int slot = (byteoff >> 4) & 3;
      const int ksw  = (slot ^ ((cl >> 1) & 3)) << 4;
      const char* bsrc = (const char*)Wbf + (size_t)(col0 + cl) * 1024 + kb * 64 + ksw;
      char* bdst = (char*)(&Bb[buf][0]) + byteoff;
      __builtin_amdgcn_global_load_lds(
          (const __attribute__((address_space(1))) void*)bsrc,
          (__attribute__((address_space(3))) void*)bdst, 16, 0, 0);
    }
  };

  stage(0, 0);
  stage(1, 1);   // 6 loads in flight

  for (int kb = 0; kb < NKB; ++kb) {
    const int cur = kb % 3;
    if (kb + 1 < NKB) {
      asm volatile("s_waitcnt vmcnt(3)" ::: "memory");  // tile kb landed
    } else {
      asm volatile("s_waitcnt vmcnt(0)" ::: "memory");
    }
    __builtin_amdgcn_s_barrier();                  // cur ready AND prev consumed
    __builtin_amdgcn_sched_barrier(0);

    if (kb + 2 < NKB) stage((kb + 2) % 3, kb + 2); // overwrite prev buf (safe)

    bf16x8 af[4], bfr[4];
#pragma unroll
    for (int rf = 0; rf < 4; ++rf) {
      const int row = wr * 64 + rf * 16 + l15;     // 0..127
      const int kby = (kg ^ ((row >> 1) & 3)) << 4;
      af[rf] = *(const bf16x8*)((const char*)&Ab[cur][0] + row * 64 + kby);
    }
#pragma unroll
    for (int cf = 0; cf < 4; ++cf) {
      const int col = wc * 64 + cf * 16 + l15;     // 0..255
      const int kby = (kg ^ ((col >> 1) & 3)) << 4;
      bfr[cf] = *(const bf16x8*)((const char*)&Bb[cur][0] + col * 64 + kby);
    }

#pragma unroll
    for (int rf = 0; rf < 4; ++rf)
#pragma unroll
      for (int cf = 0; cf < 4; ++cf)
        acc[rf][cf] = __builtin_amdgcn_mfma_f32_16x16x32_bf16(
            af[rf], bfr[cf], acc[rf][cf], 0, 0, 0);
  }

  // epilogue: bias + relu + non-temporal store.
#pragma unroll
  for (int cf = 0; cf < 4; ++cf) {
    const int col = col0 + wc * 64 + cf * 16 + l15;
    const float bb = bias[col];
#pragma unroll
    for (int rf = 0; rf < 4; ++rf) {
#pragma unroll
      for (int r = 0; r < 4; ++r) {
        const int row = row0 + wr * 64 + rf * 16 + kg * 4 + r;
        if (row < NN) {
          float val = acc[rf][cf][r] + bb;
          val = val > 0.f ? val : 0.f;
          __builtin_nontemporal_store(val, &out[(size_t)row * FAN + col]);
        }
      }
    }
  }
}

// ---------------------------------------------------------------------------
// Fallback path (ws too small): round-6 proven f32 agg + f32 GEMM via d_out.
// ---------------------------------------------------------------------------
__global__ __launch_bounds__(256) void agg_fb_kernel(
    const float* __restrict__ x,
    const int* __restrict__ nb_node,
    const int* __restrict__ nb_rel,
    float* __restrict__ vf32) {
  const int wid  = __builtin_amdgcn_readfirstlane((int)(threadIdx.x >> 6));
  const int node = blockIdx.x * 4 + wid;
  const int lane = threadIdx.x & 63;

  const int eidx = node * MM + (lane & 31);
  const int pk = nb_node[eidx] | (nb_rel[eidx] << 20);

  int nbs[MM], rls[MM];
#pragma unroll
  for (int e = 0; e < MM; ++e) {
    const int p = __builtin_amdgcn_readlane(pk, e);
    nbs[e] = p & 0xFFFFF;
    rls[e] = (p >> 20) & 7;
  }

  float vf[MM];
#pragma unroll
  for (int e = 0; e < MM; ++e) {
    const int nbc = (nbs[e] < NN) ? nbs[e] : node;
    vf[e] = x[nbc * FAN + rls[e] * HH + lane];
  }
  float xr[NCAPS_];
  const int ob = node * FAN;
#pragma unroll
  for (int r = 0; r < NCAPS_; ++r) xr[r] = x[ob + r * HH + lane];

  float acc[NCAPS_];
#pragma unroll
  for (int r = 0; r < NCAPS_; ++r) acc[r] = 0.f;
#pragma unroll
  for (int e = 0; e < MM; ++e) {
    if (nbs[e] < NN) {
      const float val = vf[e];
      switch (rls[e]) {
        case 0: acc[0] += val; break;
        case 1: acc[1] += val; break;
        case 2: acc[2] += val; break;
        case 3: acc[3] += val; break;
        case 4: acc[4] += val; break;
        case 5: acc[5] += val; break;
        case 6: acc[6] += val; break;
        case 7: acc[7] += val; break;
      }
    }
  }
#pragma unroll
  for (int r = 0; r < NCAPS_; ++r)
    vf32[ob + r * HH + lane] = acc[r] + xr[r];
}

__global__ __launch_bounds__(256) void gemm_f32_kernel(
    const float* vin, const float* __restrict__ W,
    const float* __restrict__ bias, float* out) {
  const int lane = threadIdx.x & 63;
  const int wave = threadIdx.x >> 6;
  const int row0 = blockIdx.x * 64;
  const int col0 = wave * 128;
  const int l15  = lane & 15;
  const int kg   = lane >> 4;

  f32x4 acc[4][8];
#pragma unroll
  for (int rf = 0; rf < 4; ++rf)
#pragma unroll
    for (int c = 0; c < 8; ++c) acc[rf][c] = (f32x4){0.f, 0.f, 0.f, 0.f};

  for (int kb = 0; kb < FAN / 32; ++kb) {
    const int k0 = kb * 32 + kg * 8;
    bf16x8 afrag[4];
#pragma unroll
    for (int rf = 0; rf < 4; ++rf) {
      int row = row0 + rf * 16 + l15;
      if (row >= NN) row = NN - 1;
      const float* p = vin + (size_t)row * FAN + k0;
      afrag[rf] = cvt8(*(const f32x4*)p, *(const f32x4*)(p + 4));
    }
#pragma unroll
    for (int c = 0; c < 8; ++c) {
      const int col = col0 + c * 16 + l15;
      const float* q = W + (size_t)col * FAN + k0;
      bf16x8 bfrag = cvt8(*(const f32x4*)q, *(const f32x4*)(q + 4));
#pragma unroll
      for (int rf = 0; rf < 4; ++rf)
        acc[rf][c] = __builtin_amdgcn_mfma_f32_16x16x32_bf16(
            afrag[rf], bfrag, acc[rf][c], 0, 0, 0);
    }
  }

#pragma unroll
  for (int c = 0; c < 8; ++c) {
    const int col = col0 + c * 16 + l15;
    const float bb = bias[col];
#pragma unroll
    for (int rf = 0; rf < 4; ++rf)
#pragma unroll
      for (int r = 0; r < 4; ++r) {
        const int row = row0 + rf * 16 + kg * 4 + r;
        if (row < NN) {
          float val = acc[rf][c][r] + bb;
          out[(size_t)row * FAN + col] = val > 0.f ? val : 0.f;
        }
      }
  }
}

extern "C" void kernel_launch(void* const* d_in, const int* in_sizes, int n_in,
                              void* d_out, int out_size, void* d_ws, size_t ws_size,
                              hipStream_t stream) {
  const float* x  = (const float*)d_in[0];
  const float* W  = (const float*)d_in[1];
  const float* b  = (const float*)d_in[2];
  const int*   nn = (const int*)d_in[3];
  const int*   nr = (const int*)d_in[4];
  float* out = (float*)d_out;

  const size_t wbf_bytes = (size_t)FAN * FAN * sizeof(short);        // 512 KB
  const size_t vbf_bytes = (size_t)NN * FAN * sizeof(short);         // 102.4 MB
  const size_t xbf_bytes = (size_t)NN * FAN * sizeof(short);         // 102.4 MB

  short* Wbf = (short*)d_ws;
  short* vbf = (short*)((char*)d_ws + wbf_bytes);
  short* xbf = (short*)((char*)d_ws + wbf_bytes + vbf_bytes);

  if (ws_size >= wbf_bytes + vbf_bytes + xbf_bytes) {
    conv_kernel<false><<<FAN * FAN / (256 * 8), 256, 0, stream>>>(W, Wbf);
    conv_kernel<true><<<NN * FAN / (256 * 8), 256, 0, stream>>>(x, xbf);
    agg3_kernel<<<NN / 32, 256, 0, stream>>>(
        (const unsigned short*)xbf, nn, nr, (unsigned short*)vbf);
    gemm_bf_kernel<<<NRB * (FAN / BN), 512, 0, stream>>>(vbf, Wbf, b, out);
  } else {
    agg_fb_kernel<<<NN / 4, 256, 0, stream>>>(x, nn, nr, out);
    gemm_f32_kernel<<<(NN + 63) / 64, 256, 0, stream>>>(out, W, b, out);
  }
}